// Round 6
// baseline (223.752 us; speedup 1.0000x reference)
//
#include <hip/hip_runtime.h>
#include <stdint.h>

#define TOKENS 16384
#define DDIM   1024
#define NEXP   64
#define NCOL   128              // 64 gate + 64 noise cols
#define TB     32               // tokens per block
#define NBLK   (TOKENS / TB)    // 512 blocks
#define NCH    (DDIM / 32)      // 32 k-chunks of 32

typedef __attribute__((ext_vector_type(8))) short bf16x8;  // 8 bf16 = 4 VGPR
typedef __attribute__((ext_vector_type(4))) float f32x4;

// -------- device-global scratch --------
__device__ ushort g_wh[NCOL][DDIM];   // W split: high bf16
__device__ ushort g_wm[NCOL][DDIM];   // mid
__device__ ushort g_wl[NCOL][DDIM];   // low
__device__ float g_ps[NEXP];          // sum of clean router probs per expert
__device__ float g_cnt[NEXP];         // top-2 counts per expert
__device__ float g_spa[1];            // sum of softplus

// ---------------- bf16 3-way split (x = h + m + l + O(2^-27 x)) ----------------
__device__ inline ushort bf16rne(float f) {
  uint32_t u = __float_as_uint(f);
  return (ushort)((u + 0x7fffu + ((u >> 16) & 1u)) >> 16);
}
__device__ inline float bf16tof(ushort h) {
  return __uint_as_float(((uint32_t)h) << 16);
}
__device__ inline void split3(float v, ushort& h, ushort& m, ushort& l) {
  h = bf16rne(v);
  float r1 = v - bf16tof(h);     // exact (Sterbenz-style cancellation)
  m = bf16rne(r1);
  float r2 = r1 - bf16tof(m);    // exact
  l = bf16rne(r2);
}

// ---------------- JAX threefry2x32 (20 rounds) ----------------
struct U2 { uint32_t a, b; };

__host__ __device__ constexpr U2 tf2x32(uint32_t k0, uint32_t k1,
                                        uint32_t x0, uint32_t x1) {
  uint32_t ks[3] = {k0, k1, k0 ^ k1 ^ 0x1BD11BDAu};
  const uint32_t rot[2][4] = {{13u, 15u, 26u, 6u}, {17u, 29u, 16u, 24u}};
  x0 += ks[0]; x1 += ks[1];
  for (int d = 0; d < 5; ++d) {
    for (int j = 0; j < 4; ++j) {
      uint32_t r = rot[d & 1][j];
      x0 += x1;
      x1 = (x1 << r) | (x1 >> (32u - r));
      x1 ^= x0;
    }
    x0 += ks[(d + 1) % 3];
    x1 += ks[(d + 2) % 3] + (uint32_t)(d + 1);
  }
  return U2{x0, x1};
}

// JAX >=0.5 partitionable threefry: bits[i] = xor-fold(tf(key, (0, i)))
__device__ inline uint32_t noise_bits(uint32_t i) {
  constexpr U2 NK = tf2x32(0u, 0u, 0u, 12345u);   // fold_in(key(0), 12345)
  U2 o = tf2x32(NK.a, NK.b, 0u, i);
  return o.a ^ o.b;
}

// XLA ErfInv32 (Giles polynomial)
__device__ inline float xla_erfinv(float x) {
  float w = -log1pf(-x * x);
  float p;
  if (w < 5.0f) {
    w = w - 2.5f;
    p = 2.81022636e-08f;
    p = 3.43273939e-07f + p * w;
    p = -3.5233877e-06f + p * w;
    p = -4.39150654e-06f + p * w;
    p = 0.00021858087f + p * w;
    p = -0.00125372503f + p * w;
    p = -0.00417768164f + p * w;
    p = 0.246640727f + p * w;
    p = 1.50140941f + p * w;
  } else {
    w = sqrtf(w) - 3.0f;
    p = -0.000200214257f;
    p = 0.000100950558f + p * w;
    p = 0.00134934322f + p * w;
    p = -0.00367342844f + p * w;
    p = 0.00573950773f + p * w;
    p = -0.0076224613f + p * w;
    p = 0.00943887047f + p * w;
    p = 1.00167406f + p * w;
    p = 2.83297682f + p * w;
  }
  return p * x;
}

__device__ inline float noise_normal(uint32_t i) {
  uint32_t bits = noise_bits(i);
  float f = __uint_as_float((bits >> 9) | 0x3f800000u) - 1.0f;  // [0,1)
  float u = f * 2.0f + (-0.99999994f);
  u = fmaxf(u, -0.99999994f);
  return 1.41421356237f * xla_erfinv(u);
}

__device__ inline float softplus_ref(float x) {
  return fmaxf(x, 0.0f) + log1pf(expf(-fabsf(x)));
}

// ---------------- wave(64) primitives ----------------
__device__ inline float wave_max64(float v) {
  #pragma unroll
  for (int off = 32; off; off >>= 1) v = fmaxf(v, __shfl_xor(v, off, 64));
  return v;
}
__device__ inline float wave_sum64(float v) {
  #pragma unroll
  for (int off = 32; off; off >>= 1) v += __shfl_xor(v, off, 64);
  return v;
}
__device__ inline void wave_argmax64(float v, int idx, float& mv, int& mi) {
  float bv = v; int bi = idx;
  #pragma unroll
  for (int off = 32; off; off >>= 1) {
    float ov = __shfl_xor(bv, off, 64);
    int   oi = __shfl_xor(bi, off, 64);
    if (ov > bv || (ov == bv && oi < bi)) { bv = ov; bi = oi; }
  }
  mv = bv; mi = bi;
}

// ---------------- K0: split W into bf16 h/m/l, zero accumulators ----------------
__global__ __launch_bounds__(256)
void wsplit_kernel(const float* __restrict__ wg, const float* __restrict__ wn) {
  const int col = blockIdx.x;            // 0..127
  const int tid = threadIdx.x;           // 0..255, 4 k each
  const float* src = (col < NEXP) ? (wg + (size_t)col * DDIM)
                                  : (wn + (size_t)(col - NEXP) * DDIM);
  float4 v = *(const float4*)&src[tid * 4];
  ushort h[4], m[4], l[4];
  split3(v.x, h[0], m[0], l[0]);
  split3(v.y, h[1], m[1], l[1]);
  split3(v.z, h[2], m[2], l[2]);
  split3(v.w, h[3], m[3], l[3]);
  *(ushort4*)&g_wh[col][tid * 4] = make_ushort4(h[0], h[1], h[2], h[3]);
  *(ushort4*)&g_wm[col][tid * 4] = make_ushort4(m[0], m[1], m[2], m[3]);
  *(ushort4*)&g_wl[col][tid * 4] = make_ushort4(l[0], l[1], l[2], l[3]);

  if (col == 0) {   // zero loss accumulators (K0->K1 kernel boundary orders)
    if (tid < NEXP) { g_ps[tid] = 0.0f; g_cnt[tid] = 0.0f; }
    if (tid == NEXP) g_spa[0] = 0.0f;
  }
}

// ---------------- K1: barrier-free MFMA GEMM + fused router epilogue ----------------
// block = 512 threads (8 waves) = 32 tokens x 128 cols x full K.
// waves: tg = w>>2 (16-token group), cg = w&3 (32-col group).
// NO LDS staging, NO barriers in the k-loop: A fragments are loaded per-lane
// straight from x (fp32) and split3'd in registers; B fragments are loaded
// per-lane straight from the L2-resident pre-split W (g_wh/wm/wl).
// MFMA lane map (r5-verified): A/B lane l -> row l&15, k-oct l>>4 (identical
// gather on both operands, so any k-permutation cancels).
// Product set & accumulation order identical to r5 -> bit-identical output.
__global__ __launch_bounds__(512, 4)
void NoisyTopKRouter_57621281243491_kernel(
    const float* __restrict__ x, float* __restrict__ out) {
  __shared__ float lds_logits[TB][NCOL + 4];   // 16.9 KB
  __shared__ float lps[8][NEXP];
  __shared__ float lcb[8][NEXP];
  __shared__ float lspw[8];

  const int tid  = threadIdx.x;
  const int w    = tid >> 6;          // wave 0..7
  const int lane = tid & 63;
  const int tg   = w >> 2;            // token group 0..1
  const int cg   = w & 3;             // col group 0..3
  const int tok0 = blockIdx.x * TB;

  const int fr_row = lane & 15;       // fragment row within 16
  const int fr_s   = lane >> 4;       // k-oct 0..3

  // A source: x row (fp32), 8 contiguous elements at k-oct
  const float* arow = x + (size_t)(tok0 + tg * 16 + fr_row) * DDIM + fr_s * 8;
  // B source: pre-split W rows (bf16), two 16-col tiles
  const size_t bofs0 = (size_t)(cg * 32 + fr_row) * DDIM + fr_s * 8;
  const size_t bofs1 = bofs0 + (size_t)16 * DDIM;
  const ushort* wh = &g_wh[0][0];
  const ushort* wm = &g_wm[0][0];
  const ushort* wl = &g_wl[0][0];

  f32x4 acc0 = {0.f, 0.f, 0.f, 0.f};
  f32x4 acc1 = {0.f, 0.f, 0.f, 0.f};

  union BF8 { bf16x8 v; ushort u[8]; };

  for (int kc = 0; kc < NCH; ++kc) {
    const int kbase = kc * 32;

    // ---- A: load 8 fp32, split to 3x bf16x8 in registers ----
    const float4 a0 = *(const float4*)&arow[kbase];
    const float4 a1 = *(const float4*)&arow[kbase + 4];
    const float av[8] = {a0.x, a0.y, a0.z, a0.w, a1.x, a1.y, a1.z, a1.w};
    BF8 Ah, Am, Al;
    #pragma unroll
    for (int j = 0; j < 8; ++j) {
      ushort h, m, l;
      split3(av[j], h, m, l);
      Ah.u[j] = h; Am.u[j] = m; Al.u[j] = l;
    }

    // ---- col-tile 0 ----
    {
      const bf16x8 Bh = *(const bf16x8*)&wh[bofs0 + kbase];
      const bf16x8 Bm = *(const bf16x8*)&wm[bofs0 + kbase];
      const bf16x8 Bl = *(const bf16x8*)&wl[bofs0 + kbase];
      acc0 = __builtin_amdgcn_mfma_f32_16x16x32_bf16(Ah.v, Bh, acc0, 0, 0, 0);
      acc0 = __builtin_amdgcn_mfma_f32_16x16x32_bf16(Ah.v, Bm, acc0, 0, 0, 0);
      acc0 = __builtin_amdgcn_mfma_f32_16x16x32_bf16(Am.v, Bh, acc0, 0, 0, 0);
      acc0 = __builtin_amdgcn_mfma_f32_16x16x32_bf16(Ah.v, Bl, acc0, 0, 0, 0);
      acc0 = __builtin_amdgcn_mfma_f32_16x16x32_bf16(Al.v, Bh, acc0, 0, 0, 0);
      acc0 = __builtin_amdgcn_mfma_f32_16x16x32_bf16(Am.v, Bm, acc0, 0, 0, 0);
    }
    // ---- col-tile 1 ----
    {
      const bf16x8 Bh = *(const bf16x8*)&wh[bofs1 + kbase];
      const bf16x8 Bm = *(const bf16x8*)&wm[bofs1 + kbase];
      const bf16x8 Bl = *(const bf16x8*)&wl[bofs1 + kbase];
      acc1 = __builtin_amdgcn_mfma_f32_16x16x32_bf16(Ah.v, Bh, acc1, 0, 0, 0);
      acc1 = __builtin_amdgcn_mfma_f32_16x16x32_bf16(Ah.v, Bm, acc1, 0, 0, 0);
      acc1 = __builtin_amdgcn_mfma_f32_16x16x32_bf16(Am.v, Bh, acc1, 0, 0, 0);
      acc1 = __builtin_amdgcn_mfma_f32_16x16x32_bf16(Ah.v, Bl, acc1, 0, 0, 0);
      acc1 = __builtin_amdgcn_mfma_f32_16x16x32_bf16(Al.v, Bh, acc1, 0, 0, 0);
      acc1 = __builtin_amdgcn_mfma_f32_16x16x32_bf16(Am.v, Bm, acc1, 0, 0, 0);
    }
  }

  // C-write to LDS logits: D row = 4*(lane>>4)+reg, col = lane&15 (m89-verified)
  #pragma unroll
  for (int r = 0; r < 4; ++r) {
    lds_logits[tg * 16 + 4 * fr_s + r][cg * 32 + fr_row]      = acc0[r];
    lds_logits[tg * 16 + 4 * fr_s + r][cg * 32 + 16 + fr_row] = acc1[r];
  }
  __syncthreads();   // the only block-wide barrier before the epilogue

  // ---- epilogue: 4 tokens per wave, lane = expert (identical to r1 K2 math) ----
  float* out_rw  = out;                        // [16384][2]
  float* out_idx = out + 2 * TOKENS;           // [16384][2]
  float* out_rp  = out + 4 * TOKENS + 1;       // [16384][64]

  float ps_acc = 0.0f, sp_acc = 0.0f, c_acc = 0.0f;

  for (int it = 0; it < 4; ++it) {
    const int tl = w * 4 + it;
    const int t  = tok0 + tl;
    const float cl = lds_logits[tl][lane];
    const float nl = lds_logits[tl][NEXP + lane];

    // router_probs = softmax(clean)
    const float m  = wave_max64(cl);
    const float v  = expf(cl - m);
    const float Z  = wave_sum64(v);
    const float rp = v / Z;
    out_rp[(size_t)t * NEXP + lane] = rp;
    ps_acc += rp;

    // noisy logits
    const float ns  = softplus_ref(nl);
    sp_acc += ns;
    const float noi = noise_normal((uint32_t)(t * NEXP + lane));
    const float lgn = __fadd_rn(cl, __fmul_rn(noi, ns));

    const float m2 = wave_max64(lgn);
    const float v2 = expf(lgn - m2);
    const float Z2 = wave_sum64(v2);
    const float p  = v2 / Z2;

    float p1; int i1;
    wave_argmax64(p, lane, p1, i1);
    const float pm = (lane == i1) ? -3.402823466e38f : p;
    float p2; int i2;
    wave_argmax64(pm, lane, p2, i2);

    c_acc += (float)((lane == i1) + (lane == i2));

    if (lane == 0) {
      const float s = p1 + p2;
      out_rw[t * 2 + 0]  = p1 / s;
      out_rw[t * 2 + 1]  = p2 / s;
      out_idx[t * 2 + 0] = (float)i1;
      out_idx[t * 2 + 1] = (float)i2;
    }
  }

  // block-level reduce, then one atomicAdd set per block
  lps[w][lane] = ps_acc;
  lcb[w][lane] = c_acc;
  const float spw = wave_sum64(sp_acc);
  if (lane == 0) lspw[w] = spw;
  __syncthreads();
  if (tid < NEXP) {
    float a = 0.0f, b = 0.0f;
    #pragma unroll
    for (int j = 0; j < 8; ++j) { a += lps[j][tid]; b += lcb[j][tid]; }
    atomicAdd(&g_ps[tid],  a);
    atomicAdd(&g_cnt[tid], b);
  }
  if (tid == 0) {
    float s = 0.0f;
    #pragma unroll
    for (int j = 0; j < 8; ++j) s += lspw[j];
    atomicAdd(&g_spa[0], s);
  }
}

// ---------------- K3: finalize scalars ----------------
__global__ void finalize_kernel(float* __restrict__ out) {
  const int lane = threadIdx.x;
  float term = (g_cnt[lane] / (float)TOKENS) * (g_ps[lane] / (float)TOKENS);
  #pragma unroll
  for (int off = 32; off; off >>= 1) term += __shfl_xor(term, off, 64);
  if (lane == 0) {
    out[4 * TOKENS] = 0.64f * term;   // LOAD_BALANCE_WEIGHT * NUM_EXPERTS
    out[4 * TOKENS + 1 + TOKENS * NEXP] = g_spa[0] / (float)(TOKENS * NEXP);
  }
}

// ---------------- host ----------------
extern "C" void kernel_launch(void* const* d_in, const int* in_sizes, int n_in,
                              void* d_out, int out_size, void* d_ws, size_t ws_size,
                              hipStream_t stream) {
  const float* x  = (const float*)d_in[0];   // f32 [4,4096,1024]
  const float* wg = (const float*)d_in[1];   // f32 [64,1024]
  const float* wn = (const float*)d_in[2];   // f32 [64,1024]
  float* out = (float*)d_out;                // f32, 1114114 elements

  (void)d_ws; (void)ws_size; (void)in_sizes; (void)n_in; (void)out_size;

  wsplit_kernel<<<NCOL, 256, 0, stream>>>(wg, wn);
  NoisyTopKRouter_57621281243491_kernel<<<NBLK, 512, 0, stream>>>(x, out);
  finalize_kernel<<<1, 64, 0, stream>>>(out);
}

// Round 7
// 183.317 us; speedup vs baseline: 1.2206x; 1.2206x over previous
//
#include <hip/hip_runtime.h>
#include <stdint.h>

#define TOKENS 16384
#define DDIM   1024
#define NEXP   64
#define NCOL   128              // 64 gate + 64 noise cols
#define TB     32               // tokens per block
#define NBLK   (TOKENS / TB)    // 512 blocks
#define NCH    (DDIM / 32)      // 32 k-chunks of 32
#define NTILE  8                // 8 col-tiles of 16

typedef __attribute__((ext_vector_type(8))) short bf16x8;  // 8 bf16 = 4 VGPR
typedef __attribute__((ext_vector_type(4))) float f32x4;

// -------- device-global scratch --------
// W pre-split into bf16 h/m/l, stored in MFMA-fragment order:
// g_wf[p][ct][kc][lane][j] = W_p[ct*16 + (lane&15)][kc*32 + (lane>>4)*8 + j]
// -> K1's B fragment load is a single coalesced 16B/lane read.
__device__ ushort g_wf[3][NTILE][NCH][64][8];   // 768 KB, L2-resident
__device__ float g_ps[NEXP];          // sum of clean router probs per expert
__device__ float g_cnt[NEXP];         // top-2 counts per expert
__device__ float g_spa[1];            // sum of softplus

// ---------------- bf16 3-way split (x = h + m + l + O(2^-27 x)) ----------------
__device__ inline ushort bf16rne(float f) {
  uint32_t u = __float_as_uint(f);
  return (ushort)((u + 0x7fffu + ((u >> 16) & 1u)) >> 16);
}
__device__ inline float bf16tof(ushort h) {
  return __uint_as_float(((uint32_t)h) << 16);
}
__device__ inline void split3(float v, ushort& h, ushort& m, ushort& l) {
  h = bf16rne(v);
  float r1 = v - bf16tof(h);     // exact (Sterbenz-style cancellation)
  m = bf16rne(r1);
  float r2 = r1 - bf16tof(m);    // exact
  l = bf16rne(r2);
}

// ---------------- JAX threefry2x32 (20 rounds) ----------------
struct U2 { uint32_t a, b; };

__host__ __device__ constexpr U2 tf2x32(uint32_t k0, uint32_t k1,
                                        uint32_t x0, uint32_t x1) {
  uint32_t ks[3] = {k0, k1, k0 ^ k1 ^ 0x1BD11BDAu};
  const uint32_t rot[2][4] = {{13u, 15u, 26u, 6u}, {17u, 29u, 16u, 24u}};
  x0 += ks[0]; x1 += ks[1];
  for (int d = 0; d < 5; ++d) {
    for (int j = 0; j < 4; ++j) {
      uint32_t r = rot[d & 1][j];
      x0 += x1;
      x1 = (x1 << r) | (x1 >> (32u - r));
      x1 ^= x0;
    }
    x0 += ks[(d + 1) % 3];
    x1 += ks[(d + 2) % 3] + (uint32_t)(d + 1);
  }
  return U2{x0, x1};
}

// JAX >=0.5 partitionable threefry: bits[i] = xor-fold(tf(key, (0, i)))
__device__ inline uint32_t noise_bits(uint32_t i) {
  constexpr U2 NK = tf2x32(0u, 0u, 0u, 12345u);   // fold_in(key(0), 12345)
  U2 o = tf2x32(NK.a, NK.b, 0u, i);
  return o.a ^ o.b;
}

// XLA ErfInv32 (Giles polynomial)
__device__ inline float xla_erfinv(float x) {
  float w = -log1pf(-x * x);
  float p;
  if (w < 5.0f) {
    w = w - 2.5f;
    p = 2.81022636e-08f;
    p = 3.43273939e-07f + p * w;
    p = -3.5233877e-06f + p * w;
    p = -4.39150654e-06f + p * w;
    p = 0.00021858087f + p * w;
    p = -0.00125372503f + p * w;
    p = -0.00417768164f + p * w;
    p = 0.246640727f + p * w;
    p = 1.50140941f + p * w;
  } else {
    w = sqrtf(w) - 3.0f;
    p = -0.000200214257f;
    p = 0.000100950558f + p * w;
    p = 0.00134934322f + p * w;
    p = -0.00367342844f + p * w;
    p = 0.00573950773f + p * w;
    p = -0.0076224613f + p * w;
    p = 0.00943887047f + p * w;
    p = 1.00167406f + p * w;
    p = 2.83297682f + p * w;
  }
  return p * x;
}

__device__ inline float noise_normal(uint32_t i) {
  uint32_t bits = noise_bits(i);
  float f = __uint_as_float((bits >> 9) | 0x3f800000u) - 1.0f;  // [0,1)
  float u = f * 2.0f + (-0.99999994f);
  u = fmaxf(u, -0.99999994f);
  return 1.41421356237f * xla_erfinv(u);
}

__device__ inline float softplus_ref(float x) {
  return fmaxf(x, 0.0f) + log1pf(expf(-fabsf(x)));
}

// ---------------- wave(64) primitives ----------------
__device__ inline float wave_max64(float v) {
  #pragma unroll
  for (int off = 32; off; off >>= 1) v = fmaxf(v, __shfl_xor(v, off, 64));
  return v;
}
__device__ inline float wave_sum64(float v) {
  #pragma unroll
  for (int off = 32; off; off >>= 1) v += __shfl_xor(v, off, 64);
  return v;
}
__device__ inline void wave_argmax64(float v, int idx, float& mv, int& mi) {
  float bv = v; int bi = idx;
  #pragma unroll
  for (int off = 32; off; off >>= 1) {
    float ov = __shfl_xor(bv, off, 64);
    int   oi = __shfl_xor(bi, off, 64);
    if (ov > bv || (ov == bv && oi < bi)) { bv = ov; bi = oi; }
  }
  mv = bv; mi = bi;
}

// ---------------- K0: split W into fragment-ordered bf16 h/m/l ----------------
// grid = (NTILE * NCH) blocks x 64 lanes. Block (ct, kc): lane l reads the 8
// fp32 it will own in the MFMA fragment (row ct*16+(l&15), k-oct l>>4),
// splits, and writes 3 coalesced bf16x8 rows.
__global__ __launch_bounds__(64)
void wsplit_kernel(const float* __restrict__ wg, const float* __restrict__ wn) {
  const int ct   = blockIdx.x >> 5;      // col tile 0..7
  const int kc   = blockIdx.x & 31;      // k-chunk 0..31
  const int lane = threadIdx.x;          // 0..63
  const int col  = ct * 16 + (lane & 15);
  const int koff = kc * 32 + (lane >> 4) * 8;
  const float* src = (col < NEXP) ? (wg + (size_t)col * DDIM)
                                  : (wn + (size_t)(col - NEXP) * DDIM);
  const float4 v0 = *(const float4*)&src[koff];
  const float4 v1 = *(const float4*)&src[koff + 4];
  const float av[8] = {v0.x, v0.y, v0.z, v0.w, v1.x, v1.y, v1.z, v1.w};
  union BF8 { bf16x8 v; ushort u[8]; };
  BF8 H, M, L;
  #pragma unroll
  for (int j = 0; j < 8; ++j) {
    ushort h, m, l;
    split3(av[j], h, m, l);
    H.u[j] = h; M.u[j] = m; L.u[j] = l;
  }
  *(bf16x8*)&g_wf[0][ct][kc][lane][0] = H.v;
  *(bf16x8*)&g_wf[1][ct][kc][lane][0] = M.v;
  *(bf16x8*)&g_wf[2][ct][kc][lane][0] = L.v;

  if (blockIdx.x == 0) {   // zero loss accumulators (kernel boundary orders)
    g_ps[lane] = 0.0f; g_cnt[lane] = 0.0f;
    if (lane == 0) g_spa[0] = 0.0f;
  }
}

// ---------------- K1: barrier-free MFMA GEMM + fused router epilogue ----------------
// block = 512 threads (8 waves) = 32 tokens x 128 cols x full K.
// waves: tg = w>>2 (16-token group), cg = w&3 (32-col group).
// No LDS staging, no barriers in the k-loop. A fragments: per-lane fp32 load
// + in-register split3. B fragments: single coalesced 16B/lane load from the
// fragment-ordered g_wf (this is the r6 fix: 16-txn scatter -> 1-txn load).
// Product set & accumulation order identical to r5/r6 -> bit-identical output.
__global__ __launch_bounds__(512, 4)
void NoisyTopKRouter_57621281243491_kernel(
    const float* __restrict__ x, float* __restrict__ out) {
  __shared__ float lds_logits[TB][NCOL + 4];   // 16.9 KB
  __shared__ float lps[8][NEXP];
  __shared__ float lcb[8][NEXP];
  __shared__ float lspw[8];

  const int tid  = threadIdx.x;
  const int w    = tid >> 6;          // wave 0..7
  const int lane = tid & 63;
  const int tg   = w >> 2;            // token group 0..1
  const int cg   = w & 3;             // col group 0..3
  const int tok0 = blockIdx.x * TB;

  const int fr_row = lane & 15;       // fragment row within 16
  const int fr_s   = lane >> 4;       // k-oct 0..3

  // A source: x row (fp32), 8 contiguous elements at k-oct
  const float* arow = x + (size_t)(tok0 + tg * 16 + fr_row) * DDIM + fr_s * 8;

  // B source: fragment-ordered W. strides (ushorts): product 131072, tile 16384,
  // chunk 512. Wave's tiles: ct0 = cg*2, ct1 = cg*2+1.
  const ushort* wf = &g_wf[0][0][0][0][0];
  const int b00 = (cg * 2) * 16384 + lane * 8;        // tile0, product h
  const int b10 = (cg * 2 + 1) * 16384 + lane * 8;    // tile1, product h
  #define PS 131072

  f32x4 acc0 = {0.f, 0.f, 0.f, 0.f};
  f32x4 acc1 = {0.f, 0.f, 0.f, 0.f};

  union BF8 { bf16x8 v; ushort u[8]; };

  for (int kc = 0; kc < NCH; ++kc) {
    const int kbase = kc * 32;
    const int co    = kc * 512;

    // ---- A: load 8 fp32, split to 3x bf16x8 in registers ----
    const float4 a0 = *(const float4*)&arow[kbase];
    const float4 a1 = *(const float4*)&arow[kbase + 4];
    const float av[8] = {a0.x, a0.y, a0.z, a0.w, a1.x, a1.y, a1.z, a1.w};
    BF8 Ah, Am, Al;
    #pragma unroll
    for (int j = 0; j < 8; ++j) {
      ushort h, m, l;
      split3(av[j], h, m, l);
      Ah.u[j] = h; Am.u[j] = m; Al.u[j] = l;
    }

    // ---- col-tile 0 (coalesced B fragment loads) ----
    {
      const bf16x8 Bh = *(const bf16x8*)&wf[b00 + co];
      const bf16x8 Bm = *(const bf16x8*)&wf[b00 + PS + co];
      const bf16x8 Bl = *(const bf16x8*)&wf[b00 + 2 * PS + co];
      acc0 = __builtin_amdgcn_mfma_f32_16x16x32_bf16(Ah.v, Bh, acc0, 0, 0, 0);
      acc0 = __builtin_amdgcn_mfma_f32_16x16x32_bf16(Ah.v, Bm, acc0, 0, 0, 0);
      acc0 = __builtin_amdgcn_mfma_f32_16x16x32_bf16(Am.v, Bh, acc0, 0, 0, 0);
      acc0 = __builtin_amdgcn_mfma_f32_16x16x32_bf16(Ah.v, Bl, acc0, 0, 0, 0);
      acc0 = __builtin_amdgcn_mfma_f32_16x16x32_bf16(Al.v, Bh, acc0, 0, 0, 0);
      acc0 = __builtin_amdgcn_mfma_f32_16x16x32_bf16(Am.v, Bm, acc0, 0, 0, 0);
    }
    // ---- col-tile 1 ----
    {
      const bf16x8 Bh = *(const bf16x8*)&wf[b10 + co];
      const bf16x8 Bm = *(const bf16x8*)&wf[b10 + PS + co];
      const bf16x8 Bl = *(const bf16x8*)&wf[b10 + 2 * PS + co];
      acc1 = __builtin_amdgcn_mfma_f32_16x16x32_bf16(Ah.v, Bh, acc1, 0, 0, 0);
      acc1 = __builtin_amdgcn_mfma_f32_16x16x32_bf16(Ah.v, Bm, acc1, 0, 0, 0);
      acc1 = __builtin_amdgcn_mfma_f32_16x16x32_bf16(Am.v, Bh, acc1, 0, 0, 0);
      acc1 = __builtin_amdgcn_mfma_f32_16x16x32_bf16(Ah.v, Bl, acc1, 0, 0, 0);
      acc1 = __builtin_amdgcn_mfma_f32_16x16x32_bf16(Al.v, Bh, acc1, 0, 0, 0);
      acc1 = __builtin_amdgcn_mfma_f32_16x16x32_bf16(Am.v, Bm, acc1, 0, 0, 0);
    }
  }
  #undef PS

  // C-write to LDS logits: D row = 4*(lane>>4)+reg, col = lane&15 (m89-verified)
  #pragma unroll
  for (int r = 0; r < 4; ++r) {
    lds_logits[tg * 16 + 4 * fr_s + r][cg * 32 + fr_row]      = acc0[r];
    lds_logits[tg * 16 + 4 * fr_s + r][cg * 32 + 16 + fr_row] = acc1[r];
  }
  __syncthreads();   // the only block-wide barrier before the epilogue

  // ---- epilogue: 4 tokens per wave, lane = expert (identical to r1 K2 math) ----
  float* out_rw  = out;                        // [16384][2]
  float* out_idx = out + 2 * TOKENS;           // [16384][2]
  float* out_rp  = out + 4 * TOKENS + 1;       // [16384][64]

  float ps_acc = 0.0f, sp_acc = 0.0f, c_acc = 0.0f;

  for (int it = 0; it < 4; ++it) {
    const int tl = w * 4 + it;
    const int t  = tok0 + tl;
    const float cl = lds_logits[tl][lane];
    const float nl = lds_logits[tl][NEXP + lane];

    // router_probs = softmax(clean)
    const float m  = wave_max64(cl);
    const float v  = expf(cl - m);
    const float Z  = wave_sum64(v);
    const float rp = v / Z;
    out_rp[(size_t)t * NEXP + lane] = rp;
    ps_acc += rp;

    // noisy logits
    const float ns  = softplus_ref(nl);
    sp_acc += ns;
    const float noi = noise_normal((uint32_t)(t * NEXP + lane));
    const float lgn = __fadd_rn(cl, __fmul_rn(noi, ns));

    const float m2 = wave_max64(lgn);
    const float v2 = expf(lgn - m2);
    const float Z2 = wave_sum64(v2);
    const float p  = v2 / Z2;

    float p1; int i1;
    wave_argmax64(p, lane, p1, i1);
    const float pm = (lane == i1) ? -3.402823466e38f : p;
    float p2; int i2;
    wave_argmax64(pm, lane, p2, i2);

    c_acc += (float)((lane == i1) + (lane == i2));

    if (lane == 0) {
      const float s = p1 + p2;
      out_rw[t * 2 + 0]  = p1 / s;
      out_rw[t * 2 + 1]  = p2 / s;
      out_idx[t * 2 + 0] = (float)i1;
      out_idx[t * 2 + 1] = (float)i2;
    }
  }

  // block-level reduce, then one atomicAdd set per block
  lps[w][lane] = ps_acc;
  lcb[w][lane] = c_acc;
  const float spw = wave_sum64(sp_acc);
  if (lane == 0) lspw[w] = spw;
  __syncthreads();
  if (tid < NEXP) {
    float a = 0.0f, b = 0.0f;
    #pragma unroll
    for (int j = 0; j < 8; ++j) { a += lps[j][tid]; b += lcb[j][tid]; }
    atomicAdd(&g_ps[tid],  a);
    atomicAdd(&g_cnt[tid], b);
  }
  if (tid == 0) {
    float s = 0.0f;
    #pragma unroll
    for (int j = 0; j < 8; ++j) s += lspw[j];
    atomicAdd(&g_spa[0], s);
  }
}

// ---------------- K3: finalize scalars ----------------
__global__ void finalize_kernel(float* __restrict__ out) {
  const int lane = threadIdx.x;
  float term = (g_cnt[lane] / (float)TOKENS) * (g_ps[lane] / (float)TOKENS);
  #pragma unroll
  for (int off = 32; off; off >>= 1) term += __shfl_xor(term, off, 64);
  if (lane == 0) {
    out[4 * TOKENS] = 0.64f * term;   // LOAD_BALANCE_WEIGHT * NUM_EXPERTS
    out[4 * TOKENS + 1 + TOKENS * NEXP] = g_spa[0] / (float)(TOKENS * NEXP);
  }
}

// ---------------- host ----------------
extern "C" void kernel_launch(void* const* d_in, const int* in_sizes, int n_in,
                              void* d_out, int out_size, void* d_ws, size_t ws_size,
                              hipStream_t stream) {
  const float* x  = (const float*)d_in[0];   // f32 [4,4096,1024]
  const float* wg = (const float*)d_in[1];   // f32 [64,1024]
  const float* wn = (const float*)d_in[2];   // f32 [64,1024]
  float* out = (float*)d_out;                // f32, 1114114 elements

  (void)d_ws; (void)ws_size; (void)in_sizes; (void)n_in; (void)out_size;

  wsplit_kernel<<<NTILE * NCH, 64, 0, stream>>>(wg, wn);
  NoisyTopKRouter_57621281243491_kernel<<<NBLK, 512, 0, stream>>>(x, out);
  finalize_kernel<<<1, 64, 0, stream>>>(out);
}

// Round 8
// 179.666 us; speedup vs baseline: 1.2454x; 1.0203x over previous
//
#include <hip/hip_runtime.h>
#include <stdint.h>

#define TOKENS 16384
#define DDIM   1024
#define NEXP   64
#define NCOL   128              // 64 gate + 64 noise cols
#define TB     32               // tokens per block
#define NBLK   (TOKENS / TB)    // 512 blocks
#define NCH    (DDIM / 32)      // 32 k-chunks of 32
#define NTILE  8                // 8 col-tiles of 16

typedef __attribute__((ext_vector_type(8))) short bf16x8;  // 8 bf16 = 4 VGPR
typedef __attribute__((ext_vector_type(4))) float f32x4;

// -------- device-global scratch --------
// W pre-split into bf16 h/m/l, stored in MFMA-fragment order:
// g_wf[p][ct][kc][lane][j] = W_p[ct*16 + (lane&15)][kc*32 + (lane>>4)*8 + j]
// -> K1's B fragment load is a single coalesced 16B/lane read.
__device__ ushort g_wf[3][NTILE][NCH][64][8];   // 768 KB, L2-resident
__device__ float g_ps[NEXP];          // sum of clean router probs per expert
__device__ float g_cnt[NEXP];         // top-2 counts per expert
__device__ float g_spa[1];            // sum of softplus

// ---------------- bf16 3-way split (x = h + m + l + O(2^-27 x)) ----------------
__device__ inline ushort bf16rne(float f) {
  uint32_t u = __float_as_uint(f);
  return (ushort)((u + 0x7fffu + ((u >> 16) & 1u)) >> 16);
}
__device__ inline float bf16tof(ushort h) {
  return __uint_as_float(((uint32_t)h) << 16);
}
__device__ inline void split3(float v, ushort& h, ushort& m, ushort& l) {
  h = bf16rne(v);
  float r1 = v - bf16tof(h);     // exact (Sterbenz-style cancellation)
  m = bf16rne(r1);
  float r2 = r1 - bf16tof(m);    // exact
  l = bf16rne(r2);
}

// ---------------- JAX threefry2x32 (20 rounds) ----------------
struct U2 { uint32_t a, b; };

__host__ __device__ constexpr U2 tf2x32(uint32_t k0, uint32_t k1,
                                        uint32_t x0, uint32_t x1) {
  uint32_t ks[3] = {k0, k1, k0 ^ k1 ^ 0x1BD11BDAu};
  const uint32_t rot[2][4] = {{13u, 15u, 26u, 6u}, {17u, 29u, 16u, 24u}};
  x0 += ks[0]; x1 += ks[1];
  for (int d = 0; d < 5; ++d) {
    for (int j = 0; j < 4; ++j) {
      uint32_t r = rot[d & 1][j];
      x0 += x1;
      x1 = (x1 << r) | (x1 >> (32u - r));
      x1 ^= x0;
    }
    x0 += ks[(d + 1) % 3];
    x1 += ks[(d + 2) % 3] + (uint32_t)(d + 1);
  }
  return U2{x0, x1};
}

// JAX >=0.5 partitionable threefry: bits[i] = xor-fold(tf(key, (0, i)))
__device__ inline uint32_t noise_bits(uint32_t i) {
  constexpr U2 NK = tf2x32(0u, 0u, 0u, 12345u);   // fold_in(key(0), 12345)
  U2 o = tf2x32(NK.a, NK.b, 0u, i);
  return o.a ^ o.b;
}

// XLA ErfInv32 (Giles polynomial)
__device__ inline float xla_erfinv(float x) {
  float w = -log1pf(-x * x);
  float p;
  if (w < 5.0f) {
    w = w - 2.5f;
    p = 2.81022636e-08f;
    p = 3.43273939e-07f + p * w;
    p = -3.5233877e-06f + p * w;
    p = -4.39150654e-06f + p * w;
    p = 0.00021858087f + p * w;
    p = -0.00125372503f + p * w;
    p = -0.00417768164f + p * w;
    p = 0.246640727f + p * w;
    p = 1.50140941f + p * w;
  } else {
    w = sqrtf(w) - 3.0f;
    p = -0.000200214257f;
    p = 0.000100950558f + p * w;
    p = 0.00134934322f + p * w;
    p = -0.00367342844f + p * w;
    p = 0.00573950773f + p * w;
    p = -0.0076224613f + p * w;
    p = 0.00943887047f + p * w;
    p = 1.00167406f + p * w;
    p = 2.83297682f + p * w;
  }
  return p * x;
}

__device__ inline float noise_normal(uint32_t i) {
  uint32_t bits = noise_bits(i);
  float f = __uint_as_float((bits >> 9) | 0x3f800000u) - 1.0f;  // [0,1)
  float u = f * 2.0f + (-0.99999994f);
  u = fmaxf(u, -0.99999994f);
  return 1.41421356237f * xla_erfinv(u);
}

__device__ inline float softplus_ref(float x) {
  return fmaxf(x, 0.0f) + log1pf(expf(-fabsf(x)));
}

// ---------------- wave(64) primitives ----------------
__device__ inline float wave_max64(float v) {
  #pragma unroll
  for (int off = 32; off; off >>= 1) v = fmaxf(v, __shfl_xor(v, off, 64));
  return v;
}
__device__ inline float wave_sum64(float v) {
  #pragma unroll
  for (int off = 32; off; off >>= 1) v += __shfl_xor(v, off, 64);
  return v;
}
__device__ inline void wave_argmax64(float v, int idx, float& mv, int& mi) {
  float bv = v; int bi = idx;
  #pragma unroll
  for (int off = 32; off; off >>= 1) {
    float ov = __shfl_xor(bv, off, 64);
    int   oi = __shfl_xor(bi, off, 64);
    if (ov > bv || (ov == bv && oi < bi)) { bv = ov; bi = oi; }
  }
  mv = bv; mi = bi;
}

// ---------------- K0: split W into fragment-ordered bf16 h/m/l ----------------
__global__ __launch_bounds__(64)
void wsplit_kernel(const float* __restrict__ wg, const float* __restrict__ wn) {
  const int ct   = blockIdx.x >> 5;      // col tile 0..7
  const int kc   = blockIdx.x & 31;      // k-chunk 0..31
  const int lane = threadIdx.x;          // 0..63
  const int col  = ct * 16 + (lane & 15);
  const int koff = kc * 32 + (lane >> 4) * 8;
  const float* src = (col < NEXP) ? (wg + (size_t)col * DDIM)
                                  : (wn + (size_t)(col - NEXP) * DDIM);
  const float4 v0 = *(const float4*)&src[koff];
  const float4 v1 = *(const float4*)&src[koff + 4];
  const float av[8] = {v0.x, v0.y, v0.z, v0.w, v1.x, v1.y, v1.z, v1.w};
  union BF8 { bf16x8 v; ushort u[8]; };
  BF8 H, M, L;
  #pragma unroll
  for (int j = 0; j < 8; ++j) {
    ushort h, m, l;
    split3(av[j], h, m, l);
    H.u[j] = h; M.u[j] = m; L.u[j] = l;
  }
  *(bf16x8*)&g_wf[0][ct][kc][lane][0] = H.v;
  *(bf16x8*)&g_wf[1][ct][kc][lane][0] = M.v;
  *(bf16x8*)&g_wf[2][ct][kc][lane][0] = L.v;

  if (blockIdx.x == 0) {   // zero loss accumulators (kernel boundary orders)
    g_ps[lane] = 0.0f; g_cnt[lane] = 0.0f;
    if (lane == 0) g_spa[0] = 0.0f;
  }
}

// ---------------- K1: barrier-free MFMA GEMM, reg-double-buffered ----------------
// block = 512 threads (8 waves) = 32 tokens x 128 cols x full K.
// waves: tg = w>>2 (16-token group), cg = w&3 (32-col group).
// k-loop register pipeline: chunk kc+1's A (2x float4) and B (6x bf16x8) are
// loaded into "next" registers BEFORE chunk kc's split3+MFMA, so load latency
// hides under ~300 cyc of compute x 4 waves/SIMD. Base VGPR was 36; +~40
// prefetch regs stays under the __launch_bounds__(512,4) budget of 128
// (r3's spill was at 64 acc regs + 128-thread config; not comparable).
// Product set & accumulation order identical to r5-r7 -> bit-identical output.
__global__ __launch_bounds__(512, 4)
void NoisyTopKRouter_57621281243491_kernel(
    const float* __restrict__ x, float* __restrict__ out) {
  __shared__ float lds_logits[TB][NCOL + 4];   // 16.9 KB
  __shared__ float lps[8][NEXP];
  __shared__ float lcb[8][NEXP];
  __shared__ float lspw[8];

  const int tid  = threadIdx.x;
  const int w    = tid >> 6;          // wave 0..7
  const int lane = tid & 63;
  const int tg   = w >> 2;            // token group 0..1
  const int cg   = w & 3;             // col group 0..3
  const int tok0 = blockIdx.x * TB;

  const int fr_row = lane & 15;       // fragment row within 16
  const int fr_s   = lane >> 4;       // k-oct 0..3

  // A source: x row (fp32), 8 contiguous elements at k-oct
  const float* arow = x + (size_t)(tok0 + tg * 16 + fr_row) * DDIM + fr_s * 8;

  // B source: fragment-ordered W. strides (ushorts): product 131072, tile 16384,
  // chunk 512. Wave's tiles: ct0 = cg*2, ct1 = cg*2+1.
  const ushort* wf = &g_wf[0][0][0][0][0];
  const int b00 = (cg * 2) * 16384 + lane * 8;        // tile0, product h
  const int b10 = (cg * 2 + 1) * 16384 + lane * 8;    // tile1, product h
  #define PS 131072

  f32x4 acc0 = {0.f, 0.f, 0.f, 0.f};
  f32x4 acc1 = {0.f, 0.f, 0.f, 0.f};

  union BF8 { bf16x8 v; ushort u[8]; };

  // ---- pipeline prologue: load chunk 0 into "cur" regs ----
  float4 a0c = *(const float4*)&arow[0];
  float4 a1c = *(const float4*)&arow[4];
  bf16x8 B0hc = *(const bf16x8*)&wf[b00];
  bf16x8 B0mc = *(const bf16x8*)&wf[b00 + PS];
  bf16x8 B0lc = *(const bf16x8*)&wf[b00 + 2 * PS];
  bf16x8 B1hc = *(const bf16x8*)&wf[b10];
  bf16x8 B1mc = *(const bf16x8*)&wf[b10 + PS];
  bf16x8 B1lc = *(const bf16x8*)&wf[b10 + 2 * PS];

  #pragma unroll 2
  for (int kc = 0; kc < NCH; ++kc) {
    // ---- issue next chunk's loads (clamped redundant load on the last) ----
    const int kn = (kc + 1 < NCH) ? kc + 1 : kc;
    const int kbn = kn * 32;
    const int con = kn * 512;
    const float4 a0n = *(const float4*)&arow[kbn];
    const float4 a1n = *(const float4*)&arow[kbn + 4];
    const bf16x8 B0hn = *(const bf16x8*)&wf[b00 + con];
    const bf16x8 B0mn = *(const bf16x8*)&wf[b00 + PS + con];
    const bf16x8 B0ln = *(const bf16x8*)&wf[b00 + 2 * PS + con];
    const bf16x8 B1hn = *(const bf16x8*)&wf[b10 + con];
    const bf16x8 B1mn = *(const bf16x8*)&wf[b10 + PS + con];
    const bf16x8 B1ln = *(const bf16x8*)&wf[b10 + 2 * PS + con];

    // ---- compute on cur: split A, 12 MFMAs ----
    const float av[8] = {a0c.x, a0c.y, a0c.z, a0c.w, a1c.x, a1c.y, a1c.z, a1c.w};
    BF8 Ah, Am, Al;
    #pragma unroll
    for (int j = 0; j < 8; ++j) {
      ushort h, m, l;
      split3(av[j], h, m, l);
      Ah.u[j] = h; Am.u[j] = m; Al.u[j] = l;
    }

    acc0 = __builtin_amdgcn_mfma_f32_16x16x32_bf16(Ah.v, B0hc, acc0, 0, 0, 0);
    acc0 = __builtin_amdgcn_mfma_f32_16x16x32_bf16(Ah.v, B0mc, acc0, 0, 0, 0);
    acc0 = __builtin_amdgcn_mfma_f32_16x16x32_bf16(Am.v, B0hc, acc0, 0, 0, 0);
    acc0 = __builtin_amdgcn_mfma_f32_16x16x32_bf16(Ah.v, B0lc, acc0, 0, 0, 0);
    acc0 = __builtin_amdgcn_mfma_f32_16x16x32_bf16(Al.v, B0hc, acc0, 0, 0, 0);
    acc0 = __builtin_amdgcn_mfma_f32_16x16x32_bf16(Am.v, B0mc, acc0, 0, 0, 0);

    acc1 = __builtin_amdgcn_mfma_f32_16x16x32_bf16(Ah.v, B1hc, acc1, 0, 0, 0);
    acc1 = __builtin_amdgcn_mfma_f32_16x16x32_bf16(Ah.v, B1mc, acc1, 0, 0, 0);
    acc1 = __builtin_amdgcn_mfma_f32_16x16x32_bf16(Am.v, B1hc, acc1, 0, 0, 0);
    acc1 = __builtin_amdgcn_mfma_f32_16x16x32_bf16(Ah.v, B1lc, acc1, 0, 0, 0);
    acc1 = __builtin_amdgcn_mfma_f32_16x16x32_bf16(Al.v, B1hc, acc1, 0, 0, 0);
    acc1 = __builtin_amdgcn_mfma_f32_16x16x32_bf16(Am.v, B1mc, acc1, 0, 0, 0);

    // ---- rotate next -> cur (register moves; folded by unroll) ----
    a0c = a0n; a1c = a1n;
    B0hc = B0hn; B0mc = B0mn; B0lc = B0ln;
    B1hc = B1hn; B1mc = B1mn; B1lc = B1ln;
  }
  #undef PS

  // C-write to LDS logits: D row = 4*(lane>>4)+reg, col = lane&15 (m89-verified)
  #pragma unroll
  for (int r = 0; r < 4; ++r) {
    lds_logits[tg * 16 + 4 * fr_s + r][cg * 32 + fr_row]      = acc0[r];
    lds_logits[tg * 16 + 4 * fr_s + r][cg * 32 + 16 + fr_row] = acc1[r];
  }
  __syncthreads();   // the only block-wide barrier before the epilogue

  // ---- epilogue: 4 tokens per wave, lane = expert (identical to r1 K2 math) ----
  float* out_rw  = out;                        // [16384][2]
  float* out_idx = out + 2 * TOKENS;           // [16384][2]
  float* out_rp  = out + 4 * TOKENS + 1;       // [16384][64]

  float ps_acc = 0.0f, sp_acc = 0.0f, c_acc = 0.0f;

  for (int it = 0; it < 4; ++it) {
    const int tl = w * 4 + it;
    const int t  = tok0 + tl;
    const float cl = lds_logits[tl][lane];
    const float nl = lds_logits[tl][NEXP + lane];

    // router_probs = softmax(clean)
    const float m  = wave_max64(cl);
    const float v  = expf(cl - m);
    const float Z  = wave_sum64(v);
    const float rp = v / Z;
    out_rp[(size_t)t * NEXP + lane] = rp;
    ps_acc += rp;

    // noisy logits
    const float ns  = softplus_ref(nl);
    sp_acc += ns;
    const float noi = noise_normal((uint32_t)(t * NEXP + lane));
    const float lgn = __fadd_rn(cl, __fmul_rn(noi, ns));

    const float m2 = wave_max64(lgn);
    const float v2 = expf(lgn - m2);
    const float Z2 = wave_sum64(v2);
    const float p  = v2 / Z2;

    float p1; int i1;
    wave_argmax64(p, lane, p1, i1);
    const float pm = (lane == i1) ? -3.402823466e38f : p;
    float p2; int i2;
    wave_argmax64(pm, lane, p2, i2);

    c_acc += (float)((lane == i1) + (lane == i2));

    if (lane == 0) {
      const float s = p1 + p2;
      out_rw[t * 2 + 0]  = p1 / s;
      out_rw[t * 2 + 1]  = p2 / s;
      out_idx[t * 2 + 0] = (float)i1;
      out_idx[t * 2 + 1] = (float)i2;
    }
  }

  // block-level reduce, then one atomicAdd set per block
  lps[w][lane] = ps_acc;
  lcb[w][lane] = c_acc;
  const float spw = wave_sum64(sp_acc);
  if (lane == 0) lspw[w] = spw;
  __syncthreads();
  if (tid < NEXP) {
    float a = 0.0f, b = 0.0f;
    #pragma unroll
    for (int j = 0; j < 8; ++j) { a += lps[j][tid]; b += lcb[j][tid]; }
    atomicAdd(&g_ps[tid],  a);
    atomicAdd(&g_cnt[tid], b);
  }
  if (tid == 0) {
    float s = 0.0f;
    #pragma unroll
    for (int j = 0; j < 8; ++j) s += lspw[j];
    atomicAdd(&g_spa[0], s);
  }
}

// ---------------- K3: finalize scalars ----------------
__global__ void finalize_kernel(float* __restrict__ out) {
  const int lane = threadIdx.x;
  float term = (g_cnt[lane] / (float)TOKENS) * (g_ps[lane] / (float)TOKENS);
  #pragma unroll
  for (int off = 32; off; off >>= 1) term += __shfl_xor(term, off, 64);
  if (lane == 0) {
    out[4 * TOKENS] = 0.64f * term;   // LOAD_BALANCE_WEIGHT * NUM_EXPERTS
    out[4 * TOKENS + 1 + TOKENS * NEXP] = g_spa[0] / (float)(TOKENS * NEXP);
  }
}

// ---------------- host ----------------
extern "C" void kernel_launch(void* const* d_in, const int* in_sizes, int n_in,
                              void* d_out, int out_size, void* d_ws, size_t ws_size,
                              hipStream_t stream) {
  const float* x  = (const float*)d_in[0];   // f32 [4,4096,1024]
  const float* wg = (const float*)d_in[1];   // f32 [64,1024]
  const float* wn = (const float*)d_in[2];   // f32 [64,1024]
  float* out = (float*)d_out;                // f32, 1114114 elements

  (void)d_ws; (void)ws_size; (void)in_sizes; (void)n_in; (void)out_size;

  wsplit_kernel<<<NTILE * NCH, 64, 0, stream>>>(wg, wn);
  NoisyTopKRouter_57621281243491_kernel<<<NBLK, 512, 0, stream>>>(x, out);
  finalize_kernel<<<1, 64, 0, stream>>>(out);
}